// Round 3
// baseline (322.081 us; speedup 1.0000x reference)
//
#include <hip/hip_runtime.h>
#include <hip/hip_bf16.h>
#include <stdint.h>

// GatheringLoss: score = q[32768x512] @ items[4096x512]^T, idx = argmax_row,
// out = mean((q - items[idx])^2).
// R3: 8-phase 256^2 schedule (T3+T4) + st-swizzle (T2) + setprio (T5) + XCD
// chunk (T1). 8 waves (2Mx4N), BK=64, 128KiB dbuf LDS, counted vmcnt(4) at
// phases 4/8 only. Quadrant order (A0B0),(A0B1),(A1B1),(A1B0); per-phase
// half-tile stage: ph1:(k+1)A1 ph2:(k+1)B0 ph3:(k+2)A0 ph4:(k+2)B1
// ph5:(k+2)A1 ph6:(k+2)B0 ph7:(k+3)A0 ph8:(k+3)B1.
// Swizzle: LDS slot (row,s) holds global k-slot s^(row&7); staged via
// inverse-swizzled global source (linear LDS dest), read with same XOR.
//
// ws: [0,32MB) q_fp16 | [+4MB) items_fp16 | [+1MB) val[8][32768] f32
//     | [+1MB) idx[8][32768] i32 | [+1KB) partials[256]

#define D_DIM 512
#define M_ITEMS 4096
#define N_ROWS 32768
#define BM 256
#define BN 256
#define BK 64
#define NT (D_DIM / BK) // 8 K-tiles
#define NSPLIT 8
#define TPB 2            // col-tiles per block
#define MROWS 128        // rows per merge_loss block

typedef _Float16 half8 __attribute__((ext_vector_type(8)));
typedef _Float16 half4h __attribute__((ext_vector_type(4)));
typedef float f32x4 __attribute__((ext_vector_type(4)));

#define GLD_LDS16(g, l)                                                        \
  __builtin_amdgcn_global_load_lds(                                            \
      (__attribute__((address_space(1))) const void*)(g),                      \
      (__attribute__((address_space(3))) void*)(l), 16, 0, 0)

#define BAR() __builtin_amdgcn_s_barrier()
#define SCHEDB() __builtin_amdgcn_sched_barrier(0)
#define VMW4() asm volatile("s_waitcnt vmcnt(4)" ::: "memory")
#define VMW0() asm volatile("s_waitcnt vmcnt(0)" ::: "memory")

__global__ __launch_bounds__(256) void cast_f32_f16(
    const float* __restrict__ in, _Float16* __restrict__ out, int n4) {
  const int stride = gridDim.x * blockDim.x;
  for (int i = blockIdx.x * blockDim.x + threadIdx.x; i < n4; i += stride) {
    const float4 v = reinterpret_cast<const float4*>(in)[i];
    half4h h;
    h.x = (_Float16)v.x;
    h.y = (_Float16)v.y;
    h.z = (_Float16)v.z;
    h.w = (_Float16)v.w;
    reinterpret_cast<half4h*>(out)[i] = h;
  }
}

// stage one half-tile: 2 x global_load_lds(16B)/thread, lane-linear LDS dest,
// inverse-swizzled global k-slot source.
#define STAGE_A(kt, h)                                                         \
  do {                                                                         \
    const _Float16* g =                                                        \
        qh + (size_t)(row0 + (h) * 128 + srow) * D_DIM + (kt) * BK + sswz;     \
    _Float16* l = &lds[(kt) & 1][0][h][0] + t * 8;                             \
    GLD_LDS16(g, l);                                                           \
    GLD_LDS16(g + (size_t)64 * D_DIM, l + 4096);                               \
  } while (0)

#define STAGE_B(kt, h)                                                         \
  do {                                                                         \
    const _Float16* g =                                                        \
        ih + (size_t)(col0 + (h) * 128 + srow) * D_DIM + (kt) * BK + sswz;     \
    _Float16* l = &lds[(kt) & 1][1][h][0] + t * 8;                             \
    GLD_LDS16(g, l);                                                           \
    GLD_LDS16(g + (size_t)64 * D_DIM, l + 4096);                               \
  } while (0)

#define LOAD_A(kt, ah)                                                         \
  do {                                                                         \
    const _Float16* Ab = &lds[(kt) & 1][0][ah][0];                             \
    _Pragma("unroll") for (int fr = 0; fr < 4; ++fr) {                         \
      const _Float16* rp = Ab + (size_t)(wm * 64 + fr * 16 + ln) * 64;         \
      af[fr][0] = *(const half8*)(rp + fsw0);                                  \
      af[fr][1] = *(const half8*)(rp + fsw1);                                  \
    }                                                                          \
  } while (0)

#define LOAD_B(kt, bh, BF)                                                     \
  do {                                                                         \
    const _Float16* Bb = &lds[(kt) & 1][1][bh][0];                             \
    _Pragma("unroll") for (int fc = 0; fc < 2; ++fc) {                         \
      const _Float16* rp = Bb + (size_t)(wn * 32 + fc * 16 + ln) * 64;         \
      BF[fc][0] = *(const half8*)(rp + fsw0);                                  \
      BF[fc][1] = *(const half8*)(rp + fsw1);                                  \
    }                                                                          \
  } while (0)

#define MMA_Q(ah, bh, BF)                                                      \
  do {                                                                         \
    _Pragma("unroll") for (int fr = 0; fr < 4; ++fr)                           \
        _Pragma("unroll") for (int fc = 0; fc < 2; ++fc) {                     \
      acc[(ah) * 2 + (bh)][fr][fc] = __builtin_amdgcn_mfma_f32_16x16x32_f16(   \
          af[fr][0], BF[fc][0], acc[(ah) * 2 + (bh)][fr][fc], 0, 0, 0);        \
      acc[(ah) * 2 + (bh)][fr][fc] = __builtin_amdgcn_mfma_f32_16x16x32_f16(   \
          af[fr][1], BF[fc][1], acc[(ah) * 2 + (bh)][fr][fc], 0, 0, 0);        \
    }                                                                          \
  } while (0)

__global__ __launch_bounds__(512, 2) void score_argmax(
    const _Float16* __restrict__ qh, const _Float16* __restrict__ ih,
    float* __restrict__ valArr, int* __restrict__ idxArr) {
  __shared__ _Float16 lds[2][2][2][128 * 64]; // [dbuf][A/B][half] 128 KiB

  const int t = threadIdx.x; // 0..511
  const int lane = t & 63;
  const int wid = t >> 6; // 0..7
  const int wm = wid >> 2; // 0..1
  const int wn = wid & 3;  // 0..3
  const int ln = lane & 15;
  const int lg = lane >> 4; // 0..3

  // T1: XCD-chunked bid swizzle (1024 = 8 XCD x (16 rb x 8 cs))
  const int bid = blockIdx.x;
  const int rb = (bid & 7) * 16 + ((bid >> 3) >> 3);
  const int cs = (bid >> 3) & 7;
  const int row0 = rb * BM;

  // staging invariants: thread t stages 16B slots t and t+512 of each half
  const int srow = t >> 3;                             // row (l=0)
  const int sswz = (((t & 7) ^ ((t >> 3) & 7))) * 8;   // swizzled k-slot (elems)
  // fragment-read swizzled slot offsets (elements) for ksub=0,1
  const int fsw0 = ((lg) ^ (ln & 7)) * 8;
  const int fsw1 = ((4 + lg) ^ (ln & 7)) * 8;

  half8 af[4][2], bf0[2][2], bf1[2][2];
  f32x4 acc[4][4][2];

  float tbv = -3.0e38f;
  int tbi = 0;

#pragma unroll 1
  for (int tile = 0; tile < TPB; ++tile) {
    const int col0 = cs * (TPB * BN) + tile * BN;
#pragma unroll
    for (int q = 0; q < 4; ++q)
#pragma unroll
      for (int fr = 0; fr < 4; ++fr)
#pragma unroll
        for (int fc = 0; fc < 2; ++fc)
          acc[q][fr][fc] = (f32x4){0.0f, 0.0f, 0.0f, 0.0f};

    // prologue: k0 fully + k1 {A0,B1}; vmcnt(4) -> k0 landed
    STAGE_A(0, 0);
    STAGE_B(0, 1);
    STAGE_A(0, 1);
    STAGE_B(0, 0);
    STAGE_A(1, 0);
    STAGE_B(1, 1);
    VMW4();
    BAR();
    SCHEDB();

#pragma unroll 1
    for (int kt = 0; kt < NT; kt += 2) {
      const int k1 = kt + 1, k2 = kt + 2, k3 = kt + 3;
      // ph1: Q(A0,B0) of kt
      LOAD_A(kt, 0);
      LOAD_B(kt, 0, bf0);
      STAGE_A(k1, 1);
      BAR();
      __builtin_amdgcn_s_setprio(1);
      MMA_Q(0, 0, bf0);
      __builtin_amdgcn_s_setprio(0);
      BAR();
      SCHEDB();
      // ph2: Q(A0,B1)
      LOAD_B(kt, 1, bf1);
      STAGE_B(k1, 0);
      BAR();
      __builtin_amdgcn_s_setprio(1);
      MMA_Q(0, 1, bf1);
      __builtin_amdgcn_s_setprio(0);
      BAR();
      SCHEDB();
      // ph3: Q(A1,B1)
      LOAD_A(kt, 1);
      if (k2 < NT) STAGE_A(k2, 0);
      BAR();
      __builtin_amdgcn_s_setprio(1);
      MMA_Q(1, 1, bf1);
      __builtin_amdgcn_s_setprio(0);
      BAR();
      SCHEDB();
      // ph4: Q(A1,B0); counted wait -> k1 fully landed
      if (k2 < NT) STAGE_B(k2, 1);
      BAR();
      __builtin_amdgcn_s_setprio(1);
      MMA_Q(1, 0, bf0);
      __builtin_amdgcn_s_setprio(0);
      if (k2 < NT) {
        VMW4();
      } else {
        VMW0();
      }
      BAR();
      SCHEDB();
      // ph5: Q(A0,B0) of k1
      LOAD_A(k1, 0);
      LOAD_B(k1, 0, bf0);
      if (k2 < NT) STAGE_A(k2, 1);
      BAR();
      __builtin_amdgcn_s_setprio(1);
      MMA_Q(0, 0, bf0);
      __builtin_amdgcn_s_setprio(0);
      BAR();
      SCHEDB();
      // ph6: Q(A0,B1)
      LOAD_B(k1, 1, bf1);
      if (k2 < NT) STAGE_B(k2, 0);
      BAR();
      __builtin_amdgcn_s_setprio(1);
      MMA_Q(0, 1, bf1);
      __builtin_amdgcn_s_setprio(0);
      BAR();
      SCHEDB();
      // ph7: Q(A1,B1)
      LOAD_A(k1, 1);
      if (k3 < NT) STAGE_A(k3, 0);
      BAR();
      __builtin_amdgcn_s_setprio(1);
      MMA_Q(1, 1, bf1);
      __builtin_amdgcn_s_setprio(0);
      BAR();
      SCHEDB();
      // ph8: Q(A1,B0); counted wait -> k2 fully landed
      if (k3 < NT) STAGE_B(k3, 1);
      BAR();
      __builtin_amdgcn_s_setprio(1);
      MMA_Q(1, 0, bf0);
      __builtin_amdgcn_s_setprio(0);
      if (k3 < NT) VMW4();
      BAR();
      SCHEDB();
    }

    // epilogue: fold acc -> per-row (max, idx) for this 256-col tile
    VMW0();
    BAR();
    float* sV = (float*)(&lds[0][0][0][0]); // [4][256]
    int* sI = (int*)(sV + 4 * 256);
#pragma unroll
    for (int ah = 0; ah < 2; ++ah)
#pragma unroll
      for (int fr = 0; fr < 4; ++fr)
#pragma unroll
        for (int r = 0; r < 4; ++r) {
          float v = acc[ah * 2][fr][0][r];
          int c = col0 + wn * 32 + ln;
#pragma unroll
          for (int bh = 0; bh < 2; ++bh)
#pragma unroll
            for (int fc = 0; fc < 2; ++fc) {
              if (bh == 0 && fc == 0) continue;
              const float vv = acc[ah * 2 + bh][fr][fc][r];
              const int cc = col0 + bh * 128 + wn * 32 + fc * 16 + ln;
              if (vv > v) { // cols increase over (bh,fc): ties keep lowest
                v = vv;
                c = cc;
              }
            }
#pragma unroll
          for (int m = 1; m < 16; m <<= 1) {
            const float ov = __shfl_xor(v, m, 64);
            const int oc = __shfl_xor(c, m, 64);
            if (ov > v || (ov == v && oc < c)) {
              v = ov;
              c = oc;
            }
          }
          if (ln == 0) {
            const int row = ah * 128 + wm * 64 + fr * 16 + lg * 4 + r;
            sV[wn * 256 + row] = v;
            sI[wn * 256 + row] = c;
          }
        }
    __syncthreads();
    if (t < 256) {
      float bv = sV[t];
      int bi = sI[t];
#pragma unroll
      for (int w = 1; w < 4; ++w) {
        const float v = sV[w * 256 + t];
        const int ii = sI[w * 256 + t];
        if (v > bv || (v == bv && ii < bi)) {
          bv = v;
          bi = ii;
        }
      }
      if (bv > tbv || (bv == tbv && bi < tbi)) { // tile0 cols < tile1 cols
        tbv = bv;
        tbi = bi;
      }
    }
    __syncthreads(); // LDS free for next tile's staging
  }

  if (t < 256) {
    valArr[(size_t)cs * N_ROWS + row0 + t] = tbv;
    idxArr[(size_t)cs * N_ROWS + row0 + t] = tbi;
  }
}

__global__ __launch_bounds__(256) void merge_loss(
    const float* __restrict__ qf, const float* __restrict__ itf,
    const float* __restrict__ valArr, const int* __restrict__ idxArr,
    float* __restrict__ partials) {
  __shared__ float sSum[4];
  const int t = threadIdx.x;
  const int lane = t & 63;
  const int wv = t >> 6;
  const int row0 = blockIdx.x * MROWS;

  float lsum = 0.0f;
  for (int rr = 0; rr < 32; ++rr) {
    const int row = row0 + wv * 32 + rr;
    float bv = valArr[row];
    int bi = idxArr[row];
#pragma unroll
    for (int s = 1; s < NSPLIT; ++s) {
      const float v = valArr[(size_t)s * N_ROWS + row];
      const int ii = idxArr[(size_t)s * N_ROWS + row];
      if (v > bv || (v == bv && ii < bi)) {
        bv = v;
        bi = ii;
      }
    }
    const float* qr = qf + (size_t)row * D_DIM + lane * 8;
    const float* gr = itf + (size_t)bi * D_DIM + lane * 8;
    const float4 a0 = reinterpret_cast<const float4*>(qr)[0];
    const float4 a1 = reinterpret_cast<const float4*>(qr)[1];
    const float4 b0 = reinterpret_cast<const float4*>(gr)[0];
    const float4 b1 = reinterpret_cast<const float4*>(gr)[1];
    const float d0 = a0.x - b0.x, d1 = a0.y - b0.y;
    const float d2 = a0.z - b0.z, d3 = a0.w - b0.w;
    const float d4 = a1.x - b1.x, d5 = a1.y - b1.y;
    const float d6 = a1.z - b1.z, d7 = a1.w - b1.w;
    lsum += d0 * d0 + d1 * d1 + d2 * d2 + d3 * d3 + d4 * d4 + d5 * d5 +
            d6 * d6 + d7 * d7;
  }
#pragma unroll
  for (int m = 1; m < 64; m <<= 1) lsum += __shfl_xor(lsum, m, 64);
  if (lane == 0) sSum[wv] = lsum;
  __syncthreads();
  if (t == 0) partials[blockIdx.x] = sSum[0] + sSum[1] + sSum[2] + sSum[3];
}

__global__ __launch_bounds__(256) void final_reduce(
    const float* __restrict__ partials, float* __restrict__ out) {
  __shared__ float sS[4];
  const int t = threadIdx.x;
  float v = partials[t]; // exactly 256 partials
#pragma unroll
  for (int m = 1; m < 64; m <<= 1) v += __shfl_xor(v, m, 64);
  if ((t & 63) == 0) sS[t >> 6] = v;
  __syncthreads();
  if (t == 0)
    out[0] = (sS[0] + sS[1] + sS[2] + sS[3]) *
             (1.0f / ((float)N_ROWS * (float)D_DIM));
}

extern "C" void kernel_launch(void* const* d_in, const int* in_sizes, int n_in,
                              void* d_out, int out_size, void* d_ws,
                              size_t ws_size, hipStream_t stream) {
  const float* qf = (const float*)d_in[0];  // [32768][512]
  const float* itf = (const float*)d_in[1]; // [4096][512]
  char* ws = (char*)d_ws;
  _Float16* qh = (_Float16*)ws;                                // 32 MB
  _Float16* ih = (_Float16*)(ws + (size_t)N_ROWS * D_DIM * 2); // 4 MB
  char* p = ws + (size_t)N_ROWS * D_DIM * 2 + (size_t)M_ITEMS * D_DIM * 2;
  float* valArr = (float*)p;                                   // 1 MB
  int* idxArr = (int*)(p + (size_t)NSPLIT * N_ROWS * 4);       // 1 MB
  float* partials = (float*)(p + (size_t)2 * NSPLIT * N_ROWS * 4);
  float* out = (float*)d_out;

  cast_f32_f16<<<2048, 256, 0, stream>>>(qf, qh, N_ROWS * D_DIM / 4);
  cast_f32_f16<<<512, 256, 0, stream>>>(itf, ih, M_ITEMS * D_DIM / 4);
  score_argmax<<<(N_ROWS / BM) * NSPLIT, 512, 0, stream>>>(qh, ih, valArr,
                                                           idxArr);
  merge_loss<<<N_ROWS / MROWS, 256, 0, stream>>>(qf, itf, valArr, idxArr,
                                                 partials);
  final_reduce<<<1, 256, 0, stream>>>(partials, out);
}

// Round 4
// 275.062 us; speedup vs baseline: 1.1709x; 1.1709x over previous
//
#include <hip/hip_runtime.h>
#include <hip/hip_bf16.h>
#include <stdint.h>

// GatheringLoss: score = q[32768x512] @ items[4096x512]^T, idx = argmax_row,
// out = mean((q - items[idx])^2).
// R4: 256^2 tile, 8 waves (2Mx4N), BK=64, ONE barrier per K-step, 2-deep
// pipeline: stage(k+1) issued right after barrier, waited by vmcnt(0) at
// NEXT step's top (stage latency hidden under 64 MFMAs). Keeps R3's verified
// XOR-swizzled staging (0 bank conflicts). Register-economical inner loop
// (per-ksub frag reload) to avoid R3's scratch spills (WRITE_SIZE 55MB).
// NSPLIT=2 -> grid 256 = 1 block/CU, 8 col-tiles x 8 K-steps per block.
//
// ws: [0,32MB) q_fp16 | [+4MB) items_fp16 | [+256KB) val[2][32768] f32
//     | [+256KB) idx[2][32768] i32 | [+1KB) partials[256]

#define D_DIM 512
#define M_ITEMS 4096
#define N_ROWS 32768
#define BM 256
#define BN 256
#define BK 64
#define NT (D_DIM / BK)  // 8 K-steps
#define NSPLIT 2
#define NCT 8            // col-tiles per block (4096 / NSPLIT / 256)
#define MROWS 128        // rows per merge_loss block

typedef _Float16 half8 __attribute__((ext_vector_type(8)));
typedef _Float16 half4h __attribute__((ext_vector_type(4)));
typedef float f32x4 __attribute__((ext_vector_type(4)));

#define GLD_LDS16(g, l)                                                        \
  __builtin_amdgcn_global_load_lds(                                            \
      (__attribute__((address_space(1))) const void*)(g),                      \
      (__attribute__((address_space(3))) void*)(l), 16, 0, 0)

#define BAR() __builtin_amdgcn_s_barrier()
#define SCHEDB() __builtin_amdgcn_sched_barrier(0)
#define VMW0() asm volatile("s_waitcnt vmcnt(0)" ::: "memory")

__global__ __launch_bounds__(256) void cast_f32_f16(
    const float* __restrict__ in, _Float16* __restrict__ out, int n4) {
  const int stride = gridDim.x * blockDim.x;
  for (int i = blockIdx.x * blockDim.x + threadIdx.x; i < n4; i += stride) {
    const float4 v = reinterpret_cast<const float4*>(in)[i];
    half4h h;
    h.x = (_Float16)v.x;
    h.y = (_Float16)v.y;
    h.z = (_Float16)v.z;
    h.w = (_Float16)v.w;
    reinterpret_cast<half4h*>(out)[i] = h;
  }
}

// stage one 256x64 fp16 tile (32KB): 4 x global_load_lds(16B)/thread.
// Thread t stages 16B slots {t + i*512}; slot = row*8 + s, content k-slot
// s ^ (row&7) (inverse-swizzled global source, lane-linear LDS dest).
#define STAGE_OP(ptr, base_row, kt, bufsel, op)                                \
  do {                                                                         \
    const _Float16* g =                                                        \
        (ptr) + (size_t)((base_row) + srow) * D_DIM + (kt) * BK + sswz;        \
    _Float16* l = &lds[bufsel][op][0] + t * 8;                                 \
    GLD_LDS16(g, l);                                                           \
    GLD_LDS16(g + (size_t)64 * D_DIM, l + 4096);                               \
    GLD_LDS16(g + (size_t)128 * D_DIM, l + 8192);                              \
    GLD_LDS16(g + (size_t)192 * D_DIM, l + 12288);                             \
  } while (0)

__global__ __launch_bounds__(512, 2) void score_argmax(
    const _Float16* __restrict__ qh, const _Float16* __restrict__ ih,
    float* __restrict__ valArr, int* __restrict__ idxArr) {
  __shared__ _Float16 lds[2][2][BM * BK]; // [dbuf][A/B] 128 KiB
  __shared__ float sV[4][256];            // 4 KiB
  __shared__ int sI[4][256];              // 4 KiB

  const int t = threadIdx.x; // 0..511
  const int lane = t & 63;
  const int wid = t >> 6;  // 0..7
  const int wm = wid >> 2; // 0..1 (row half)
  const int wn = wid & 3;  // 0..3 (col quarter)
  const int ln = lane & 15;
  const int lg = lane >> 4; // 0..3

  // T1: bijective XCD chunking (grid 256 = 8 XCD x 32)
  const int bid = blockIdx.x;
  const int wgid = (bid & 7) * 32 + (bid >> 3);
  const int rb = wgid >> 1;  // 0..127
  const int cs = wgid & 1;   // col split
  const int row0 = rb * BM;

  // staging offsets (same for all 4 chunks: (srow+64i)&7 == srow&7)
  const int srow = t >> 3;
  const int sswz = ((t & 7) ^ (srow & 7)) * 8;
  // fragment-read swizzled k-slot offsets (elements) per ksub
  const int fsw0 = (lg ^ (ln & 7)) * 8;
  const int fsw1 = ((4 + lg) ^ (ln & 7)) * 8;

  f32x4 acc[8][4];
  float tbv = -3.0e38f;
  int tbi = 0;

  // prologue: stage (ct=0, ks=0) into buf0
  STAGE_OP(qh, row0, 0, 0, 0);
  {
    const int c0 = cs * (NCT * BN);
    STAGE_OP(ih, c0, 0, 0, 1);
  }

#pragma unroll 1
  for (int ct = 0; ct < NCT; ++ct) {
    const int col0 = cs * (NCT * BN) + ct * BN;
#pragma unroll
    for (int fr = 0; fr < 8; ++fr)
#pragma unroll
      for (int fc = 0; fc < 4; ++fc)
        acc[fr][fc] = (f32x4){0.0f, 0.0f, 0.0f, 0.0f};

#pragma unroll 1
    for (int ks = 0; ks < NT; ++ks) {
      const int cur = ks & 1;
      VMW0();          // my stage of buf[cur] (issued last step) complete
      BAR();           // everyone's complete
      SCHEDB();
      // issue next stage first (full K-step + latency to land)
      if (ks < NT - 1) {
        STAGE_OP(qh, row0, ks + 1, cur ^ 1, 0);
        STAGE_OP(ih, col0, ks + 1, cur ^ 1, 1);
      } else if (ct < NCT - 1) {
        STAGE_OP(qh, row0, 0, 0, 0);
        STAGE_OP(ih, col0 + BN, 0, 0, 1);
      }
      // compute buf[cur]: 2 ksub x (12 ds_read_b128 + 32 MFMA)
      const _Float16* Ab = &lds[cur][0][0];
      const _Float16* Bb = &lds[cur][1][0];
#pragma unroll
      for (int ksub = 0; ksub < 2; ++ksub) {
        const int fsw = ksub ? fsw1 : fsw0;
        half8 af[8], bf[4];
#pragma unroll
        for (int fr = 0; fr < 8; ++fr)
          af[fr] =
              *(const half8*)(Ab + (size_t)(wm * 128 + fr * 16 + ln) * 64 + fsw);
#pragma unroll
        for (int fc = 0; fc < 4; ++fc)
          bf[fc] =
              *(const half8*)(Bb + (size_t)(wn * 64 + fc * 16 + ln) * 64 + fsw);
#pragma unroll
        for (int fr = 0; fr < 8; ++fr)
#pragma unroll
          for (int fc = 0; fc < 4; ++fc)
            acc[fr][fc] = __builtin_amdgcn_mfma_f32_16x16x32_f16(
                af[fr], bf[fc], acc[fr][fc], 0, 0, 0);
      }
    }

    // epilogue: fold acc -> per-row (max, idx) for this 256-col tile.
    // C layout: col=lane&15, row=(lane>>4)*4+reg (m89-verified).
#pragma unroll
    for (int fr = 0; fr < 8; ++fr)
#pragma unroll
      for (int r = 0; r < 4; ++r) {
        float v = acc[fr][0][r];
        int c = col0 + wn * 64 + ln;
#pragma unroll
        for (int fc = 1; fc < 4; ++fc) {
          const float vv = acc[fr][fc][r];
          const int cc = col0 + wn * 64 + fc * 16 + ln;
          if (vv > v) { // cols increase with fc: strict > keeps lowest
            v = vv;
            c = cc;
          }
        }
#pragma unroll
        for (int m = 1; m < 16; m <<= 1) {
          const float ov = __shfl_xor(v, m, 64);
          const int oc = __shfl_xor(c, m, 64);
          if (ov > v || (ov == v && oc < c)) {
            v = ov;
            c = oc;
          }
        }
        if (ln == 0) {
          const int row = wm * 128 + fr * 16 + lg * 4 + r;
          sV[wn][row] = v;
          sI[wn][row] = c;
        }
      }
    __syncthreads();
    if (t < 256) {
      float bv = sV[0][t];
      int bi = sI[0][t];
#pragma unroll
      for (int w = 1; w < 4; ++w) {
        const float v = sV[w][t];
        const int ii = sI[w][t];
        if (v > bv || (v == bv && ii < bi)) {
          bv = v;
          bi = ii;
        }
      }
      if (bv > tbv || (bv == tbv && bi < tbi)) { // later ct = higher cols
        tbv = bv;
        tbi = bi;
      }
    }
    __syncthreads(); // sV/sI reads done before next ct's epilogue writes
  }

  if (t < 256) {
    valArr[(size_t)cs * N_ROWS + row0 + t] = tbv;
    idxArr[(size_t)cs * N_ROWS + row0 + t] = tbi;
  }
}

__global__ __launch_bounds__(256) void merge_loss(
    const float* __restrict__ qf, const float* __restrict__ itf,
    const float* __restrict__ valArr, const int* __restrict__ idxArr,
    float* __restrict__ partials) {
  __shared__ float sSum[4];
  const int t = threadIdx.x;
  const int lane = t & 63;
  const int wv = t >> 6;
  const int row0 = blockIdx.x * MROWS;

  float lsum = 0.0f;
  for (int rr = 0; rr < 32; ++rr) {
    const int row = row0 + wv * 32 + rr;
    float bv = valArr[row];
    int bi = idxArr[row];
#pragma unroll
    for (int s = 1; s < NSPLIT; ++s) {
      const float v = valArr[(size_t)s * N_ROWS + row];
      const int ii = idxArr[(size_t)s * N_ROWS + row];
      if (v > bv || (v == bv && ii < bi)) {
        bv = v;
        bi = ii;
      }
    }
    const float* qr = qf + (size_t)row * D_DIM + lane * 8;
    const float* gr = itf + (size_t)bi * D_DIM + lane * 8;
    const float4 a0 = reinterpret_cast<const float4*>(qr)[0];
    const float4 a1 = reinterpret_cast<const float4*>(qr)[1];
    const float4 b0 = reinterpret_cast<const float4*>(gr)[0];
    const float4 b1 = reinterpret_cast<const float4*>(gr)[1];
    const float d0 = a0.x - b0.x, d1 = a0.y - b0.y;
    const float d2 = a0.z - b0.z, d3 = a0.w - b0.w;
    const float d4 = a1.x - b1.x, d5 = a1.y - b1.y;
    const float d6 = a1.z - b1.z, d7 = a1.w - b1.w;
    lsum += d0 * d0 + d1 * d1 + d2 * d2 + d3 * d3 + d4 * d4 + d5 * d5 +
            d6 * d6 + d7 * d7;
  }
#pragma unroll
  for (int m = 1; m < 64; m <<= 1) lsum += __shfl_xor(lsum, m, 64);
  if (lane == 0) sSum[wv] = lsum;
  __syncthreads();
  if (t == 0) partials[blockIdx.x] = sSum[0] + sSum[1] + sSum[2] + sSum[3];
}

__global__ __launch_bounds__(256) void final_reduce(
    const float* __restrict__ partials, float* __restrict__ out) {
  __shared__ float sS[4];
  const int t = threadIdx.x;
  float v = partials[t]; // exactly 256 partials
#pragma unroll
  for (int m = 1; m < 64; m <<= 1) v += __shfl_xor(v, m, 64);
  if ((t & 63) == 0) sS[t >> 6] = v;
  __syncthreads();
  if (t == 0)
    out[0] = (sS[0] + sS[1] + sS[2] + sS[3]) *
             (1.0f / ((float)N_ROWS * (float)D_DIM));
}

extern "C" void kernel_launch(void* const* d_in, const int* in_sizes, int n_in,
                              void* d_out, int out_size, void* d_ws,
                              size_t ws_size, hipStream_t stream) {
  const float* qf = (const float*)d_in[0];  // [32768][512]
  const float* itf = (const float*)d_in[1]; // [4096][512]
  char* ws = (char*)d_ws;
  _Float16* qh = (_Float16*)ws;                                // 32 MB
  _Float16* ih = (_Float16*)(ws + (size_t)N_ROWS * D_DIM * 2); // 4 MB
  char* p = ws + (size_t)N_ROWS * D_DIM * 2 + (size_t)M_ITEMS * D_DIM * 2;
  float* valArr = (float*)p;                                   // 256 KB
  int* idxArr = (int*)(p + (size_t)NSPLIT * N_ROWS * 4);       // 256 KB
  float* partials = (float*)(p + (size_t)2 * NSPLIT * N_ROWS * 4);
  float* out = (float*)d_out;

  cast_f32_f16<<<2048, 256, 0, stream>>>(qf, qh, N_ROWS * D_DIM / 4);
  cast_f32_f16<<<512, 256, 0, stream>>>(itf, ih, M_ITEMS * D_DIM / 4);
  score_argmax<<<(N_ROWS / BM) * NSPLIT, 512, 0, stream>>>(qh, ih, valArr,
                                                           idxArr);
  merge_loss<<<N_ROWS / MROWS, 256, 0, stream>>>(qf, itf, valArr, idxArr,
                                                 partials);
  final_reduce<<<1, 256, 0, stream>>>(partials, out);
}